// Round 12
// baseline (362.794 us; speedup 1.0000x reference)
//
#include <hip/hip_runtime.h>
#include <stdint.h>

#define SHIFT 4
#define EPS 1e-5f

#define B_ 8
#define C_ 256
#define H_ 128
#define W_ 128
#define HW_ (H_*W_)
#define NWIN 2048            // 8 * 16 * 16 windows

typedef unsigned short u16;
typedef float f32x4 __attribute__((ext_vector_type(4)));
typedef __bf16 bf16x8 __attribute__((ext_vector_type(8)));
typedef unsigned short u16x8 __attribute__((ext_vector_type(8)));
typedef unsigned short u16x4 __attribute__((ext_vector_type(4)));

static __device__ __forceinline__ u16 f2bf(float f) {
    uint32_t u = __builtin_bit_cast(uint32_t, f);
    u = u + 0x7fffu + ((u >> 16) & 1u);
    return (u16)(u >> 16);
}
static __device__ __forceinline__ float bf2f(u16 u) {
    return __builtin_bit_cast(float, (uint32_t)u << 16);
}

// ---------------- K0: weight prep into per-fragment streaming order ----------------
// W2q: qkv B-frags: [jg(48)][kt(8)][lane(64)][e(8)]  <- wqkv[k][col], col=jg*16+(l&15), k=kt*32+(l>>4)*8+e
// W2pA: proj A-frags (operand-swapped): [ig(16)][kt(8)][lane(64)][e(8)] <- wproj[k][c], c=ig*16+(l&15)
__global__ __launch_bounds__(256) void k_prep_w(const float* __restrict__ wqkv,
                                                const float* __restrict__ wproj,
                                                u16* __restrict__ W2q, u16* __restrict__ W2pA) {
    int i = blockIdx.x * 256 + threadIdx.x;   // 0 .. 262143
    if (i < 48 * 8 * 64 * 8) {
        int e = i & 7, l = (i >> 3) & 63, kt = (i >> 9) & 7, jg = i >> 12;
        int col = jg * 16 + (l & 15);
        int k = kt * 32 + (l >> 4) * 8 + e;
        W2q[i] = f2bf(wqkv[k * 768 + col]);
    } else {
        int j = i - 48 * 8 * 64 * 8;          // < 65536
        int e = j & 7, l = (j >> 3) & 63, kt = (j >> 9) & 7, ig = j >> 12;
        int c = ig * 16 + (l & 15);
        int k = kt * 32 + (l >> 4) * 8 + e;
        W2pA[j] = f2bf(wproj[k * 256 + c]);
    }
}

// ---------------- K1: LN stats + LN + shift + window partition -> frag-ordered ywin ----------------
// ywin2[win][kt(8)][i(4)][lane(64)][e(8)]: value y[token = i*16+(lane&15)][c = kt*32+(lane>>4)*8+e]
__global__ __launch_bounds__(256) void k_ln_win(const float* __restrict__ x,
                                                const float* __restrict__ g,
                                                const float* __restrict__ beta,
                                                u16* __restrict__ ywin2) {
    __shared__ u16 sv[256][130];
    __shared__ float ps[2][128];
    __shared__ float pss[2][128];
    __shared__ float mval[128];
    __shared__ float rval[128];
    int h = blockIdx.x;
    int b = blockIdx.y;
    int t = threadIdx.x;
    int p = t >> 7, w = t & 127;
    const float* xb = x + (size_t)b * C_ * HW_ + (size_t)h * W_;
    float s = 0.f, ss = 0.f;
    #pragma unroll 8
    for (int it = 0; it < 128; ++it) {
        int c = it * 2 + p;
        float v = xb[(size_t)c * HW_ + w];
        s += v; ss += v * v;
        sv[c][w] = f2bf(v);
    }
    ps[p][w] = s;
    pss[p][w] = ss;
    __syncthreads();
    if (t < 128) {
        float st = ps[0][t] + ps[1][t];
        float sst = pss[0][t] + pss[1][t];
        float m = st * (1.f / C_);
        float var = sst * (1.f / C_) - m * m;
        mval[t] = m;
        rval[t] = rsqrtf(var + EPS);
    }
    __syncthreads();
    int hp = (h - SHIFT) & 127;
    int wh = hp >> 3, r = hp & 7;
    int i_f = r >> 1;                 // token = r*8+s -> frag i
    int lrb = (r & 1) * 8;            // frag lane-row base
    int c = t;
    float gc = g[c], bc = beta[c];
    int kt = c >> 5, lk2 = (c >> 3) & 3, e = c & 7;
    int winrow = (b * 16 + wh) * 16;
    u16* dst = ywin2 + (size_t)winrow * 16384 + kt * 2048 + i_f * 512 + lk2 * 128 + lrb * 8 + e;
    #pragma unroll 4
    for (int wp = 0; wp < 128; ++wp) {
        int wsrc = (wp + SHIFT) & 127;
        float v = bf2f(sv[c][wsrc]);
        float yv = (v - mval[wsrc]) * rval[wsrc] * gc + bc;
        dst[(size_t)(wp >> 3) * 16384 + (wp & 7) * 8] = f2bf(yv);
    }
}

// ---------------- K2: MEGA: qkv + attention + proj + residual, per-wave head ownership ----------------
// 1 block = 1 window, 512 thr = 8 waves, wave = head. LDS 80 KiB -> 2 blocks/CU.
// Per-wave region 10240 B: Q[64][40] @0 | K[64][40] @2560u16; VT[32][72] overlays Q;
// Phalf[64][40] overlays K. O[64][280] overlays everything after barrier.
// R12: 1-deep even/odd register pipeline on the A-operand streams (af / a2).
__global__ __launch_bounds__(512, 4) void k_fused(const u16* __restrict__ ywin2,
                                                  const u16* __restrict__ W2q,
                                                  const u16* __restrict__ W2pA,
                                                  const float* __restrict__ bqkv,
                                                  const float* __restrict__ bproj,
                                                  const float* __restrict__ x,
                                                  float* __restrict__ out) {
    extern __shared__ __align__(16) char smem[];
    int bid = blockIdx.x;
    int win = (bid & 7) * 256 + (bid >> 3);      // XCD-chunked
    int b = win >> 8, wh = (win >> 4) & 15, ww = win & 15;
    int t = threadIdx.x;
    int wave = t >> 6, lane = t & 63;
    int lr = lane & 15, lk = lane >> 4;
    int hd = wave;

    u16* WR = (u16*)smem + wave * 5120;   // u16 units
    u16* Q  = WR;
    u16* K  = WR + 2560;
    u16* VT = WR;          // overlay Q (Q dead after qf reads)
    u16* Ph = WR + 2560;   // overlay K (K dead after kf reads)
    u16* O  = (u16*)smem;  // [64][280] after barrier

    const u16* afp = ywin2 + (size_t)win * 16384;

    // ---- qk-pass: acc[i][jl], jl: 0,1=q d0/d1; 2,3=k d0/d1 ----
    f32x4 acc[4][4];
    #pragma unroll
    for (int i = 0; i < 4; ++i)
        #pragma unroll
        for (int j = 0; j < 4; ++j) acc[i][j] = (f32x4){0.f,0.f,0.f,0.f};
    {
        bf16x8 afA[4], afB[4];
        #pragma unroll
        for (int i = 0; i < 4; ++i)
            afA[i] = __builtin_bit_cast(bf16x8, *(const u16x8*)(afp + i * 512 + lane * 8));
        #pragma unroll
        for (int kp = 0; kp < 4; ++kp) {
            {
                const int kt = 2 * kp;
                #pragma unroll
                for (int i = 0; i < 4; ++i)
                    afB[i] = __builtin_bit_cast(bf16x8, *(const u16x8*)(afp + (kt + 1) * 2048 + i * 512 + lane * 8));
                bf16x8 bq[4];
                #pragma unroll
                for (int jl = 0; jl < 4; ++jl) {
                    int jg = (jl >> 1) * 16 + 2 * hd + (jl & 1);
                    bq[jl] = __builtin_bit_cast(bf16x8, *(const u16x8*)(W2q + ((size_t)(jg * 8 + kt)) * 512 + lane * 8));
                }
                #pragma unroll
                for (int i = 0; i < 4; ++i)
                    #pragma unroll
                    for (int jl = 0; jl < 4; ++jl)
                        acc[i][jl] = __builtin_amdgcn_mfma_f32_16x16x32_bf16(afA[i], bq[jl], acc[i][jl], 0, 0, 0);
            }
            {
                const int kt = 2 * kp + 1;
                if (kp < 3) {
                    #pragma unroll
                    for (int i = 0; i < 4; ++i)
                        afA[i] = __builtin_bit_cast(bf16x8, *(const u16x8*)(afp + (kt + 1) * 2048 + i * 512 + lane * 8));
                }
                bf16x8 bq[4];
                #pragma unroll
                for (int jl = 0; jl < 4; ++jl) {
                    int jg = (jl >> 1) * 16 + 2 * hd + (jl & 1);
                    bq[jl] = __builtin_bit_cast(bf16x8, *(const u16x8*)(W2q + ((size_t)(jg * 8 + kt)) * 512 + lane * 8));
                }
                #pragma unroll
                for (int i = 0; i < 4; ++i)
                    #pragma unroll
                    for (int jl = 0; jl < 4; ++jl)
                        acc[i][jl] = __builtin_amdgcn_mfma_f32_16x16x32_bf16(afB[i], bq[jl], acc[i][jl], 0, 0, 0);
            }
        }
    }
    // stage Q, K (pad-40)
    #pragma unroll
    for (int jl = 0; jl < 4; ++jl) {
        int which = jl >> 1;
        int d = (jl & 1) * 16 + lr;
        float bi = bqkv[which * 256 + hd * 32 + d];
        u16* dst = which ? K : Q;
        #pragma unroll
        for (int i = 0; i < 4; ++i)
            #pragma unroll
            for (int rg = 0; rg < 4; ++rg)
                dst[(i * 16 + lk * 4 + rg) * 40 + d] = f2bf(acc[i][jl][rg] + bi);
    }
    // ---- S = Q K^T ----
    bf16x8 qf[4], kf[4];
    #pragma unroll
    for (int i = 0; i < 4; ++i)
        qf[i] = __builtin_bit_cast(bf16x8, *(const u16x8*)(&Q[(i * 16 + lr) * 40 + lk * 8]));
    #pragma unroll
    for (int j = 0; j < 4; ++j)
        kf[j] = __builtin_bit_cast(bf16x8, *(const u16x8*)(&K[(j * 16 + lr) * 40 + lk * 8]));
    f32x4 s[4][4];
    #pragma unroll
    for (int i = 0; i < 4; ++i)
        #pragma unroll
        for (int j = 0; j < 4; ++j) s[i][j] = (f32x4){0.f,0.f,0.f,0.f};
    #pragma unroll
    for (int i = 0; i < 4; ++i)
        #pragma unroll
        for (int j = 0; j < 4; ++j)
            s[i][j] = __builtin_amdgcn_mfma_f32_16x16x32_bf16(qf[i], kf[j], s[i][j], 0, 0, 0);

    // ---- softmax (max-sub, wave-parallel over 16-lane groups) ----
    const float scale = 0.17677669529663687f;   // 32^-0.5
    #pragma unroll
    for (int i = 0; i < 4; ++i) {
        #pragma unroll
        for (int rg = 0; rg < 4; ++rg) {
            float s0 = s[i][0][rg] * scale, s1 = s[i][1][rg] * scale;
            float s2 = s[i][2][rg] * scale, s3 = s[i][3][rg] * scale;
            float mx = fmaxf(fmaxf(s0, s1), fmaxf(s2, s3));
            mx = fmaxf(mx, __shfl_xor(mx, 1));
            mx = fmaxf(mx, __shfl_xor(mx, 2));
            mx = fmaxf(mx, __shfl_xor(mx, 4));
            mx = fmaxf(mx, __shfl_xor(mx, 8));
            float p0 = __expf(s0 - mx), p1 = __expf(s1 - mx);
            float p2 = __expf(s2 - mx), p3 = __expf(s3 - mx);
            float sm = p0 + p1 + p2 + p3;
            sm += __shfl_xor(sm, 1);
            sm += __shfl_xor(sm, 2);
            sm += __shfl_xor(sm, 4);
            sm += __shfl_xor(sm, 8);
            float rs = 1.f / sm;
            s[i][0][rg] = p0 * rs; s[i][1][rg] = p1 * rs;
            s[i][2][rg] = p2 * rs; s[i][3][rg] = p3 * rs;
        }
    }
    // write P half 0 (k 0..31)
    #pragma unroll
    for (int j2 = 0; j2 < 2; ++j2)
        #pragma unroll
        for (int i = 0; i < 4; ++i)
            #pragma unroll
            for (int rg = 0; rg < 4; ++rg)
                Ph[(i * 16 + lk * 4 + rg) * 40 + j2 * 16 + lr] = f2bf(s[i][j2][rg]);

    // ---- v-pass: av[i][jl], 1-deep af pipeline ----
    f32x4 av[4][2];
    #pragma unroll
    for (int i = 0; i < 4; ++i)
        #pragma unroll
        for (int j = 0; j < 2; ++j) av[i][j] = (f32x4){0.f,0.f,0.f,0.f};
    {
        bf16x8 afA[4], afB[4];
        #pragma unroll
        for (int i = 0; i < 4; ++i)
            afA[i] = __builtin_bit_cast(bf16x8, *(const u16x8*)(afp + i * 512 + lane * 8));
        #pragma unroll
        for (int kp = 0; kp < 4; ++kp) {
            {
                const int kt = 2 * kp;
                #pragma unroll
                for (int i = 0; i < 4; ++i)
                    afB[i] = __builtin_bit_cast(bf16x8, *(const u16x8*)(afp + (kt + 1) * 2048 + i * 512 + lane * 8));
                bf16x8 bv[2];
                #pragma unroll
                for (int jl = 0; jl < 2; ++jl) {
                    int jg = 32 + 2 * hd + jl;
                    bv[jl] = __builtin_bit_cast(bf16x8, *(const u16x8*)(W2q + ((size_t)(jg * 8 + kt)) * 512 + lane * 8));
                }
                #pragma unroll
                for (int i = 0; i < 4; ++i)
                    #pragma unroll
                    for (int jl = 0; jl < 2; ++jl)
                        av[i][jl] = __builtin_amdgcn_mfma_f32_16x16x32_bf16(afA[i], bv[jl], av[i][jl], 0, 0, 0);
            }
            {
                const int kt = 2 * kp + 1;
                if (kp < 3) {
                    #pragma unroll
                    for (int i = 0; i < 4; ++i)
                        afA[i] = __builtin_bit_cast(bf16x8, *(const u16x8*)(afp + (kt + 1) * 2048 + i * 512 + lane * 8));
                }
                bf16x8 bv[2];
                #pragma unroll
                for (int jl = 0; jl < 2; ++jl) {
                    int jg = 32 + 2 * hd + jl;
                    bv[jl] = __builtin_bit_cast(bf16x8, *(const u16x8*)(W2q + ((size_t)(jg * 8 + kt)) * 512 + lane * 8));
                }
                #pragma unroll
                for (int i = 0; i < 4; ++i)
                    #pragma unroll
                    for (int jl = 0; jl < 2; ++jl)
                        av[i][jl] = __builtin_amdgcn_mfma_f32_16x16x32_bf16(afB[i], bv[jl], av[i][jl], 0, 0, 0);
            }
        }
    }
    // VT[d][tok] pad-72, packed b64 writes (VT overlays Q)
    #pragma unroll
    for (int jl = 0; jl < 2; ++jl) {
        float bi = bqkv[512 + hd * 32 + jl * 16 + lr];
        #pragma unroll
        for (int i = 0; i < 4; ++i) {
            u16x4 pk;
            #pragma unroll
            for (int rg = 0; rg < 4; ++rg) pk[rg] = f2bf(av[i][jl][rg] + bi);
            *(u16x4*)(&VT[(jl * 16 + lr) * 72 + i * 16 + lk * 4]) = pk;
        }
    }
    // ---- PV, half 0 ----
    f32x4 oacc[4][2];
    #pragma unroll
    for (int i = 0; i < 4; ++i)
        #pragma unroll
        for (int j = 0; j < 2; ++j) oacc[i][j] = (f32x4){0.f,0.f,0.f,0.f};
    {
        bf16x8 pf[4], vf[2];
        #pragma unroll
        for (int i = 0; i < 4; ++i)
            pf[i] = __builtin_bit_cast(bf16x8, *(const u16x8*)(&Ph[(i * 16 + lr) * 40 + lk * 8]));
        #pragma unroll
        for (int j = 0; j < 2; ++j)
            vf[j] = __builtin_bit_cast(bf16x8, *(const u16x8*)(&VT[(j * 16 + lr) * 72 + lk * 8]));
        #pragma unroll
        for (int i = 0; i < 4; ++i)
            #pragma unroll
            for (int j = 0; j < 2; ++j)
                oacc[i][j] = __builtin_amdgcn_mfma_f32_16x16x32_bf16(pf[i], vf[j], oacc[i][j], 0, 0, 0);
    }
    // write P half 1 (k 32..63) into same Ph region (same-wave DS ordering)
    #pragma unroll
    for (int j2 = 2; j2 < 4; ++j2)
        #pragma unroll
        for (int i = 0; i < 4; ++i)
            #pragma unroll
            for (int rg = 0; rg < 4; ++rg)
                Ph[(i * 16 + lk * 4 + rg) * 40 + (j2 & 1) * 16 + lr] = f2bf(s[i][j2][rg]);
    // ---- PV, half 1 ----
    {
        bf16x8 pf[4], vf[2];
        #pragma unroll
        for (int i = 0; i < 4; ++i)
            pf[i] = __builtin_bit_cast(bf16x8, *(const u16x8*)(&Ph[(i * 16 + lr) * 40 + lk * 8]));
        #pragma unroll
        for (int j = 0; j < 2; ++j)
            vf[j] = __builtin_bit_cast(bf16x8, *(const u16x8*)(&VT[(j * 16 + lr) * 72 + 32 + lk * 8]));
        #pragma unroll
        for (int i = 0; i < 4; ++i)
            #pragma unroll
            for (int j = 0; j < 2; ++j)
                oacc[i][j] = __builtin_amdgcn_mfma_f32_16x16x32_bf16(pf[i], vf[j], oacc[i][j], 0, 0, 0);
    }

    __syncthreads();   // all waves done with private regions -> O overlay safe
    // O[tok][c] pad-280
    #pragma unroll
    for (int i = 0; i < 4; ++i)
        #pragma unroll
        for (int j = 0; j < 2; ++j)
            #pragma unroll
            for (int rg = 0; rg < 4; ++rg)
                O[(i * 16 + lk * 4 + rg) * 280 + hd * 32 + j * 16 + lr] = f2bf(oacc[i][j][rg]);
    __syncthreads();

    // ---- proj (swapped): D[c][tok], wave covers c = wave*32 .. +31; 1-deep a2 pipeline ----
    f32x4 c2[2][4];
    #pragma unroll
    for (int i = 0; i < 2; ++i)
        #pragma unroll
        for (int j = 0; j < 4; ++j) c2[i][j] = (f32x4){0.f,0.f,0.f,0.f};
    {
        bf16x8 a2A[2], a2B[2];
        #pragma unroll
        for (int i2 = 0; i2 < 2; ++i2)
            a2A[i2] = __builtin_bit_cast(bf16x8,
                *(const u16x8*)(W2pA + ((size_t)((wave * 2 + i2) * 8)) * 512 + lane * 8));
        #pragma unroll
        for (int kp = 0; kp < 4; ++kp) {
            {
                const int kt = 2 * kp;
                #pragma unroll
                for (int i2 = 0; i2 < 2; ++i2)
                    a2B[i2] = __builtin_bit_cast(bf16x8,
                        *(const u16x8*)(W2pA + ((size_t)((wave * 2 + i2) * 8 + kt + 1)) * 512 + lane * 8));
                bf16x8 bo[4];
                #pragma unroll
                for (int j = 0; j < 4; ++j)
                    bo[j] = __builtin_bit_cast(bf16x8, *(const u16x8*)(&O[(j * 16 + lr) * 280 + kt * 32 + lk * 8]));
                #pragma unroll
                for (int i2 = 0; i2 < 2; ++i2)
                    #pragma unroll
                    for (int j = 0; j < 4; ++j)
                        c2[i2][j] = __builtin_amdgcn_mfma_f32_16x16x32_bf16(a2A[i2], bo[j], c2[i2][j], 0, 0, 0);
            }
            {
                const int kt = 2 * kp + 1;
                if (kp < 3) {
                    #pragma unroll
                    for (int i2 = 0; i2 < 2; ++i2)
                        a2A[i2] = __builtin_bit_cast(bf16x8,
                            *(const u16x8*)(W2pA + ((size_t)((wave * 2 + i2) * 8 + kt + 1)) * 512 + lane * 8));
                }
                bf16x8 bo[4];
                #pragma unroll
                for (int j = 0; j < 4; ++j)
                    bo[j] = __builtin_bit_cast(bf16x8, *(const u16x8*)(&O[(j * 16 + lr) * 280 + kt * 32 + lk * 8]));
                #pragma unroll
                for (int i2 = 0; i2 < 2; ++i2)
                    #pragma unroll
                    for (int j = 0; j < 4; ++j)
                        c2[i2][j] = __builtin_amdgcn_mfma_f32_16x16x32_bf16(a2B[i2], bo[j], c2[i2][j], 0, 0, 0);
            }
        }
    }

    // ---- epilogue: out[b][c][hs][ws] = 2*(proj + bproj + x) ----
    {
        int hbase = wh * 8 + SHIFT;
        int wbase = ww * 8 + SHIFT;
        #pragma unroll
        for (int i = 0; i < 2; ++i)
            #pragma unroll
            for (int rg = 0; rg < 4; ++rg) {
                int c = wave * 32 + i * 16 + lk * 4 + rg;
                float bi = bproj[c];
                size_t cb = ((size_t)(b * 256 + c)) << 14;
                #pragma unroll
                for (int j = 0; j < 4; ++j) {
                    int token = j * 16 + lr;
                    int r = token >> 3, sgm = token & 7;
                    int hs = (hbase + r) & 127;
                    int wc = (wbase + sgm) & 127;
                    size_t oi = cb + hs * 128 + wc;
                    out[oi] = 2.f * (c2[i][j][rg] + bi + x[oi]);
                }
            }
    }
}

extern "C" void kernel_launch(void* const* d_in, const int* in_sizes, int n_in,
                              void* d_out, int out_size, void* d_ws, size_t ws_size,
                              hipStream_t stream) {
    const float* x     = (const float*)d_in[0];
    const float* g1    = (const float*)d_in[1];
    const float* bb1   = (const float*)d_in[2];
    const float* wqkv  = (const float*)d_in[3];
    const float* bqkv  = (const float*)d_in[4];
    const float* wproj = (const float*)d_in[5];
    const float* bproj = (const float*)d_in[6];
    float* out = (float*)d_out;

    char* ws = (char*)d_ws;
    u16* W2q  = (u16*)ws;                          // 384 KiB
    u16* W2pA = (u16*)(ws + 393216);               // 128 KiB
    u16* ywin2 = (u16*)(ws + (1ull << 20));        // 64 MiB frag-ordered

    static const int LDS_BYTES = 81920;
    hipFuncSetAttribute((const void*)k_fused,
                        hipFuncAttributeMaxDynamicSharedMemorySize, LDS_BYTES);

    k_prep_w<<<1024, 256, 0, stream>>>(wqkv, wproj, W2q, W2pA);
    k_ln_win<<<dim3(128, 8), 256, 0, stream>>>(x, g1, bb1, ywin2);
    k_fused<<<NWIN, 512, LDS_BYTES, stream>>>(ywin2, W2q, W2pA, bqkv, bproj, x, out);
}

// Round 13
// 247.961 us; speedup vs baseline: 1.4631x; 1.4631x over previous
//
#include <hip/hip_runtime.h>
#include <stdint.h>

#define SHIFT 4
#define EPS 1e-5f

#define B_ 8
#define C_ 256
#define H_ 128
#define W_ 128
#define HW_ (H_*W_)
#define NWIN 2048            // 8 * 16 * 16 windows

typedef unsigned short u16;
typedef float f32x4 __attribute__((ext_vector_type(4)));
typedef __bf16 bf16x8 __attribute__((ext_vector_type(8)));
typedef unsigned short u16x8 __attribute__((ext_vector_type(8)));
typedef unsigned short u16x4 __attribute__((ext_vector_type(4)));

static __device__ __forceinline__ u16 f2bf(float f) {
    uint32_t u = __builtin_bit_cast(uint32_t, f);
    u = u + 0x7fffu + ((u >> 16) & 1u);
    return (u16)(u >> 16);
}
static __device__ __forceinline__ float bf2f(u16 u) {
    return __builtin_bit_cast(float, (uint32_t)u << 16);
}

// ---------------- K0: weight prep into per-fragment streaming order ----------------
// W2q: qkv B-frags: [jg(48)][kt(8)][lane(64)][e(8)]  <- wqkv[k][col], col=jg*16+(l&15), k=kt*32+(l>>4)*8+e
// W2pA: proj A-frags (operand-swapped): [ig(16)][kt(8)][lane(64)][e(8)] <- wproj[k][c], c=ig*16+(l&15)
__global__ __launch_bounds__(256) void k_prep_w(const float* __restrict__ wqkv,
                                                const float* __restrict__ wproj,
                                                u16* __restrict__ W2q, u16* __restrict__ W2pA) {
    int i = blockIdx.x * 256 + threadIdx.x;   // 0 .. 262143
    if (i < 48 * 8 * 64 * 8) {
        int e = i & 7, l = (i >> 3) & 63, kt = (i >> 9) & 7, jg = i >> 12;
        int col = jg * 16 + (l & 15);
        int k = kt * 32 + (l >> 4) * 8 + e;
        W2q[i] = f2bf(wqkv[k * 768 + col]);
    } else {
        int j = i - 48 * 8 * 64 * 8;          // < 65536
        int e = j & 7, l = (j >> 3) & 63, kt = (j >> 9) & 7, ig = j >> 12;
        int c = ig * 16 + (l & 15);
        int k = kt * 32 + (l >> 4) * 8 + e;
        W2pA[j] = f2bf(wproj[k * 256 + c]);
    }
}

// ---------------- K1: LN stats + LN + shift + window partition -> frag-ordered ywin ----------------
// ywin2[win][kt(8)][i(4)][lane(64)][e(8)]: value y[token = i*16+(lane&15)][c = kt*32+(lane>>4)*8+e]
__global__ __launch_bounds__(256) void k_ln_win(const float* __restrict__ x,
                                                const float* __restrict__ g,
                                                const float* __restrict__ beta,
                                                u16* __restrict__ ywin2) {
    __shared__ u16 sv[256][130];
    __shared__ float ps[2][128];
    __shared__ float pss[2][128];
    __shared__ float mval[128];
    __shared__ float rval[128];
    int h = blockIdx.x;
    int b = blockIdx.y;
    int t = threadIdx.x;
    int p = t >> 7, w = t & 127;
    const float* xb = x + (size_t)b * C_ * HW_ + (size_t)h * W_;
    float s = 0.f, ss = 0.f;
    #pragma unroll 8
    for (int it = 0; it < 128; ++it) {
        int c = it * 2 + p;
        float v = xb[(size_t)c * HW_ + w];
        s += v; ss += v * v;
        sv[c][w] = f2bf(v);
    }
    ps[p][w] = s;
    pss[p][w] = ss;
    __syncthreads();
    if (t < 128) {
        float st = ps[0][t] + ps[1][t];
        float sst = pss[0][t] + pss[1][t];
        float m = st * (1.f / C_);
        float var = sst * (1.f / C_) - m * m;
        mval[t] = m;
        rval[t] = rsqrtf(var + EPS);
    }
    __syncthreads();
    int hp = (h - SHIFT) & 127;
    int wh = hp >> 3, r = hp & 7;
    int i_f = r >> 1;                 // token = r*8+s -> frag i
    int lrb = (r & 1) * 8;            // frag lane-row base
    int c = t;
    float gc = g[c], bc = beta[c];
    int kt = c >> 5, lk2 = (c >> 3) & 3, e = c & 7;
    int winrow = (b * 16 + wh) * 16;
    u16* dst = ywin2 + (size_t)winrow * 16384 + kt * 2048 + i_f * 512 + lk2 * 128 + lrb * 8 + e;
    #pragma unroll 4
    for (int wp = 0; wp < 128; ++wp) {
        int wsrc = (wp + SHIFT) & 127;
        float v = bf2f(sv[c][wsrc]);
        float yv = (v - mval[wsrc]) * rval[wsrc] * gc + bc;
        dst[(size_t)(wp >> 3) * 16384 + (wp & 7) * 8] = f2bf(yv);
    }
}

// ---------------- K2: MEGA: qkv + attention + proj + residual, per-wave head ownership ----------------
// 1 block = 1 window, 512 thr = 8 waves, wave = head. LDS 80 KiB -> 2 blocks/CU.
// Per-wave region 10240 B: Q[64][40] @0 | K[64][40] @2560u16; VT[32][72] overlays Q;
// Phalf[64][40] overlays K. O[64][280] overlays everything after barrier.
__global__ __launch_bounds__(512, 4) void k_fused(const u16* __restrict__ ywin2,
                                                  const u16* __restrict__ W2q,
                                                  const u16* __restrict__ W2pA,
                                                  const float* __restrict__ bqkv,
                                                  const float* __restrict__ bproj,
                                                  const float* __restrict__ x,
                                                  float* __restrict__ out) {
    extern __shared__ __align__(16) char smem[];
    int bid = blockIdx.x;
    int win = (bid & 7) * 256 + (bid >> 3);      // XCD-chunked
    int b = win >> 8, wh = (win >> 4) & 15, ww = win & 15;
    int t = threadIdx.x;
    int wave = t >> 6, lane = t & 63;
    int lr = lane & 15, lk = lane >> 4;
    int hd = wave;

    u16* WR = (u16*)smem + wave * 5120;   // u16 units
    u16* Q  = WR;
    u16* K  = WR + 2560;
    u16* VT = WR;          // overlay Q (Q dead after qf reads)
    u16* Ph = WR + 2560;   // overlay K (K dead after kf reads)
    u16* O  = (u16*)smem;  // [64][280] after barrier

    const u16* afp = ywin2 + (size_t)win * 16384;

    // ---- qk-pass: acc[i][jl], jl: 0,1=q d0/d1; 2,3=k d0/d1 ----
    f32x4 acc[4][4];
    #pragma unroll
    for (int i = 0; i < 4; ++i)
        #pragma unroll
        for (int j = 0; j < 4; ++j) acc[i][j] = (f32x4){0.f,0.f,0.f,0.f};
    #pragma unroll 2
    for (int kt = 0; kt < 8; ++kt) {
        bf16x8 af[4], bq[4];
        #pragma unroll
        for (int i = 0; i < 4; ++i)
            af[i] = __builtin_bit_cast(bf16x8, *(const u16x8*)(afp + kt * 2048 + i * 512 + lane * 8));
        #pragma unroll
        for (int jl = 0; jl < 4; ++jl) {
            int jg = (jl >> 1) * 16 + 2 * hd + (jl & 1);
            bq[jl] = __builtin_bit_cast(bf16x8, *(const u16x8*)(W2q + ((size_t)(jg * 8 + kt)) * 512 + lane * 8));
        }
        #pragma unroll
        for (int i = 0; i < 4; ++i)
            #pragma unroll
            for (int jl = 0; jl < 4; ++jl)
                acc[i][jl] = __builtin_amdgcn_mfma_f32_16x16x32_bf16(af[i], bq[jl], acc[i][jl], 0, 0, 0);
    }
    // stage Q, K (pad-40)
    #pragma unroll
    for (int jl = 0; jl < 4; ++jl) {
        int which = jl >> 1;
        int d = (jl & 1) * 16 + lr;
        float bi = bqkv[which * 256 + hd * 32 + d];
        u16* dst = which ? K : Q;
        #pragma unroll
        for (int i = 0; i < 4; ++i)
            #pragma unroll
            for (int rg = 0; rg < 4; ++rg)
                dst[(i * 16 + lk * 4 + rg) * 40 + d] = f2bf(acc[i][jl][rg] + bi);
    }
    // ---- S = Q K^T ----
    bf16x8 qf[4], kf[4];
    #pragma unroll
    for (int i = 0; i < 4; ++i)
        qf[i] = __builtin_bit_cast(bf16x8, *(const u16x8*)(&Q[(i * 16 + lr) * 40 + lk * 8]));
    #pragma unroll
    for (int j = 0; j < 4; ++j)
        kf[j] = __builtin_bit_cast(bf16x8, *(const u16x8*)(&K[(j * 16 + lr) * 40 + lk * 8]));
    f32x4 s[4][4];
    #pragma unroll
    for (int i = 0; i < 4; ++i)
        #pragma unroll
        for (int j = 0; j < 4; ++j) s[i][j] = (f32x4){0.f,0.f,0.f,0.f};
    #pragma unroll
    for (int i = 0; i < 4; ++i)
        #pragma unroll
        for (int j = 0; j < 4; ++j)
            s[i][j] = __builtin_amdgcn_mfma_f32_16x16x32_bf16(qf[i], kf[j], s[i][j], 0, 0, 0);

    // ---- softmax (max-sub, wave-parallel over 16-lane groups) ----
    const float scale = 0.17677669529663687f;   // 32^-0.5
    #pragma unroll
    for (int i = 0; i < 4; ++i) {
        #pragma unroll
        for (int rg = 0; rg < 4; ++rg) {
            float s0 = s[i][0][rg] * scale, s1 = s[i][1][rg] * scale;
            float s2 = s[i][2][rg] * scale, s3 = s[i][3][rg] * scale;
            float mx = fmaxf(fmaxf(s0, s1), fmaxf(s2, s3));
            mx = fmaxf(mx, __shfl_xor(mx, 1));
            mx = fmaxf(mx, __shfl_xor(mx, 2));
            mx = fmaxf(mx, __shfl_xor(mx, 4));
            mx = fmaxf(mx, __shfl_xor(mx, 8));
            float p0 = __expf(s0 - mx), p1 = __expf(s1 - mx);
            float p2 = __expf(s2 - mx), p3 = __expf(s3 - mx);
            float sm = p0 + p1 + p2 + p3;
            sm += __shfl_xor(sm, 1);
            sm += __shfl_xor(sm, 2);
            sm += __shfl_xor(sm, 4);
            sm += __shfl_xor(sm, 8);
            float rs = 1.f / sm;
            s[i][0][rg] = p0 * rs; s[i][1][rg] = p1 * rs;
            s[i][2][rg] = p2 * rs; s[i][3][rg] = p3 * rs;
        }
    }
    // write P half 0 (k 0..31)
    #pragma unroll
    for (int j2 = 0; j2 < 2; ++j2)
        #pragma unroll
        for (int i = 0; i < 4; ++i)
            #pragma unroll
            for (int rg = 0; rg < 4; ++rg)
                Ph[(i * 16 + lk * 4 + rg) * 40 + j2 * 16 + lr] = f2bf(s[i][j2][rg]);

    // ---- v-pass: av[i][jl] ----
    f32x4 av[4][2];
    #pragma unroll
    for (int i = 0; i < 4; ++i)
        #pragma unroll
        for (int j = 0; j < 2; ++j) av[i][j] = (f32x4){0.f,0.f,0.f,0.f};
    #pragma unroll 2
    for (int kt = 0; kt < 8; ++kt) {
        bf16x8 af[4], bv[2];
        #pragma unroll
        for (int i = 0; i < 4; ++i)
            af[i] = __builtin_bit_cast(bf16x8, *(const u16x8*)(afp + kt * 2048 + i * 512 + lane * 8));
        #pragma unroll
        for (int jl = 0; jl < 2; ++jl) {
            int jg = 32 + 2 * hd + jl;
            bv[jl] = __builtin_bit_cast(bf16x8, *(const u16x8*)(W2q + ((size_t)(jg * 8 + kt)) * 512 + lane * 8));
        }
        #pragma unroll
        for (int i = 0; i < 4; ++i)
            #pragma unroll
            for (int jl = 0; jl < 2; ++jl)
                av[i][jl] = __builtin_amdgcn_mfma_f32_16x16x32_bf16(af[i], bv[jl], av[i][jl], 0, 0, 0);
    }
    // VT[d][tok] pad-72, packed b64 writes (VT overlays Q)
    #pragma unroll
    for (int jl = 0; jl < 2; ++jl) {
        float bi = bqkv[512 + hd * 32 + jl * 16 + lr];
        #pragma unroll
        for (int i = 0; i < 4; ++i) {
            u16x4 pk;
            #pragma unroll
            for (int rg = 0; rg < 4; ++rg) pk[rg] = f2bf(av[i][jl][rg] + bi);
            *(u16x4*)(&VT[(jl * 16 + lr) * 72 + i * 16 + lk * 4]) = pk;
        }
    }
    // ---- PV, half 0 ----
    f32x4 oacc[4][2];
    #pragma unroll
    for (int i = 0; i < 4; ++i)
        #pragma unroll
        for (int j = 0; j < 2; ++j) oacc[i][j] = (f32x4){0.f,0.f,0.f,0.f};
    {
        bf16x8 pf[4], vf[2];
        #pragma unroll
        for (int i = 0; i < 4; ++i)
            pf[i] = __builtin_bit_cast(bf16x8, *(const u16x8*)(&Ph[(i * 16 + lr) * 40 + lk * 8]));
        #pragma unroll
        for (int j = 0; j < 2; ++j)
            vf[j] = __builtin_bit_cast(bf16x8, *(const u16x8*)(&VT[(j * 16 + lr) * 72 + lk * 8]));
        #pragma unroll
        for (int i = 0; i < 4; ++i)
            #pragma unroll
            for (int j = 0; j < 2; ++j)
                oacc[i][j] = __builtin_amdgcn_mfma_f32_16x16x32_bf16(pf[i], vf[j], oacc[i][j], 0, 0, 0);
    }
    // write P half 1 (k 32..63) into same Ph region (same-wave DS ordering)
    #pragma unroll
    for (int j2 = 2; j2 < 4; ++j2)
        #pragma unroll
        for (int i = 0; i < 4; ++i)
            #pragma unroll
            for (int rg = 0; rg < 4; ++rg)
                Ph[(i * 16 + lk * 4 + rg) * 40 + (j2 & 1) * 16 + lr] = f2bf(s[i][j2][rg]);
    // ---- PV, half 1 ----
    {
        bf16x8 pf[4], vf[2];
        #pragma unroll
        for (int i = 0; i < 4; ++i)
            pf[i] = __builtin_bit_cast(bf16x8, *(const u16x8*)(&Ph[(i * 16 + lr) * 40 + lk * 8]));
        #pragma unroll
        for (int j = 0; j < 2; ++j)
            vf[j] = __builtin_bit_cast(bf16x8, *(const u16x8*)(&VT[(j * 16 + lr) * 72 + 32 + lk * 8]));
        #pragma unroll
        for (int i = 0; i < 4; ++i)
            #pragma unroll
            for (int j = 0; j < 2; ++j)
                oacc[i][j] = __builtin_amdgcn_mfma_f32_16x16x32_bf16(pf[i], vf[j], oacc[i][j], 0, 0, 0);
    }

    __syncthreads();   // all waves done with private regions -> O overlay safe
    // O[tok][c] pad-280
    #pragma unroll
    for (int i = 0; i < 4; ++i)
        #pragma unroll
        for (int j = 0; j < 2; ++j)
            #pragma unroll
            for (int rg = 0; rg < 4; ++rg)
                O[(i * 16 + lk * 4 + rg) * 280 + hd * 32 + j * 16 + lr] = f2bf(oacc[i][j][rg]);
    __syncthreads();

    // ---- proj (swapped): D[c][tok], wave covers c = wave*32 .. +31 ----
    f32x4 c2[2][4];
    #pragma unroll
    for (int i = 0; i < 2; ++i)
        #pragma unroll
        for (int j = 0; j < 4; ++j) c2[i][j] = (f32x4){0.f,0.f,0.f,0.f};
    #pragma unroll 2
    for (int kt = 0; kt < 8; ++kt) {
        bf16x8 a2[2], bo[4];
        #pragma unroll
        for (int i2 = 0; i2 < 2; ++i2)
            a2[i2] = __builtin_bit_cast(bf16x8,
                *(const u16x8*)(W2pA + ((size_t)((wave * 2 + i2) * 8 + kt)) * 512 + lane * 8));
        #pragma unroll
        for (int j = 0; j < 4; ++j)
            bo[j] = __builtin_bit_cast(bf16x8, *(const u16x8*)(&O[(j * 16 + lr) * 280 + kt * 32 + lk * 8]));
        #pragma unroll
        for (int i2 = 0; i2 < 2; ++i2)
            #pragma unroll
            for (int j = 0; j < 4; ++j)
                c2[i2][j] = __builtin_amdgcn_mfma_f32_16x16x32_bf16(a2[i2], bo[j], c2[i2][j], 0, 0, 0);
    }

    // ---- epilogue: out[b][c][hs][ws] = 2*(proj + bproj + x) ----
    {
        int hbase = wh * 8 + SHIFT;
        int wbase = ww * 8 + SHIFT;
        #pragma unroll
        for (int i = 0; i < 2; ++i)
            #pragma unroll
            for (int rg = 0; rg < 4; ++rg) {
                int c = wave * 32 + i * 16 + lk * 4 + rg;
                float bi = bproj[c];
                size_t cb = ((size_t)(b * 256 + c)) << 14;
                #pragma unroll
                for (int j = 0; j < 4; ++j) {
                    int token = j * 16 + lr;
                    int r = token >> 3, sgm = token & 7;
                    int hs = (hbase + r) & 127;
                    int wc = (wbase + sgm) & 127;
                    size_t oi = cb + hs * 128 + wc;
                    out[oi] = 2.f * (c2[i][j][rg] + bi + x[oi]);
                }
            }
    }
}

extern "C" void kernel_launch(void* const* d_in, const int* in_sizes, int n_in,
                              void* d_out, int out_size, void* d_ws, size_t ws_size,
                              hipStream_t stream) {
    const float* x     = (const float*)d_in[0];
    const float* g1    = (const float*)d_in[1];
    const float* bb1   = (const float*)d_in[2];
    const float* wqkv  = (const float*)d_in[3];
    const float* bqkv  = (const float*)d_in[4];
    const float* wproj = (const float*)d_in[5];
    const float* bproj = (const float*)d_in[6];
    float* out = (float*)d_out;

    char* ws = (char*)d_ws;
    u16* W2q  = (u16*)ws;                          // 384 KiB
    u16* W2pA = (u16*)(ws + 393216);               // 128 KiB
    u16* ywin2 = (u16*)(ws + (1ull << 20));        // 64 MiB frag-ordered

    static const int LDS_BYTES = 81920;
    hipFuncSetAttribute((const void*)k_fused,
                        hipFuncAttributeMaxDynamicSharedMemorySize, LDS_BYTES);

    k_prep_w<<<1024, 256, 0, stream>>>(wqkv, wproj, W2q, W2pA);
    k_ln_win<<<dim3(128, 8), 256, 0, stream>>>(x, g1, bb1, ywin2);
    k_fused<<<NWIN, 512, LDS_BYTES, stream>>>(ywin2, W2q, W2pA, bqkv, bproj, x, out);
}

// Round 14
// 235.965 us; speedup vs baseline: 1.5375x; 1.0508x over previous
//
#include <hip/hip_runtime.h>
#include <stdint.h>

#define SHIFT 4
#define EPS 1e-5f

#define B_ 8
#define C_ 256
#define H_ 128
#define W_ 128
#define HW_ (H_*W_)
#define NWIN 2048            // 8 * 16 * 16 windows

typedef unsigned short u16;
typedef float f32x4 __attribute__((ext_vector_type(4)));
typedef __bf16 bf16x8 __attribute__((ext_vector_type(8)));
typedef unsigned short u16x8 __attribute__((ext_vector_type(8)));
typedef unsigned short u16x4 __attribute__((ext_vector_type(4)));

static __device__ __forceinline__ u16 f2bf(float f) {
    uint32_t u = __builtin_bit_cast(uint32_t, f);
    u = u + 0x7fffu + ((u >> 16) & 1u);
    return (u16)(u >> 16);
}
static __device__ __forceinline__ float bf2f(u16 u) {
    return __builtin_bit_cast(float, (uint32_t)u << 16);
}

// ---------------- K1: LN stats + LN + shift + window partition -> frag-ordered ywin ----------------
// ywin2[win][kt(8)][i(4)][lane(64)][e(8)]: value y[token = i*16+(lane&15)][c = kt*32+(lane>>4)*8+e]
// Blocks x in [128,192) with y==0 additionally do the weight prep (former k_prep_w):
// W2q: qkv B-frags: [jg(48)][kt(8)][lane(64)][e(8)]  <- wqkv[k][col], col=jg*16+(l&15), k=kt*32+(l>>4)*8+e
// W2pA: proj A-frags (operand-swapped): [ig(16)][kt(8)][lane(64)][e(8)] <- wproj[k][c], c=ig*16+(l&15)
__global__ __launch_bounds__(256) void k_ln_win(const float* __restrict__ x,
                                                const float* __restrict__ g,
                                                const float* __restrict__ beta,
                                                u16* __restrict__ ywin2,
                                                const float* __restrict__ wqkv,
                                                const float* __restrict__ wproj,
                                                u16* __restrict__ W2q,
                                                u16* __restrict__ W2pA) {
    __shared__ u16 sv[256][130];
    __shared__ float ps[2][128];
    __shared__ float pss[2][128];
    __shared__ float mval[128];
    __shared__ float rval[128];
    if (blockIdx.x >= 128) {
        // ---- weight prep branch (64 blocks, y==0 only) ----
        if (blockIdx.y != 0) return;
        int base = ((blockIdx.x - 128) * 256 + threadIdx.x) * 16;
        #pragma unroll 4
        for (int q = 0; q < 16; ++q) {
            int i = base + q;
            if (i < 48 * 8 * 64 * 8) {
                int e = i & 7, l = (i >> 3) & 63, kt = (i >> 9) & 7, jg = i >> 12;
                int col = jg * 16 + (l & 15);
                int k = kt * 32 + (l >> 4) * 8 + e;
                W2q[i] = f2bf(wqkv[k * 768 + col]);
            } else {
                int j = i - 48 * 8 * 64 * 8;          // < 65536
                int e = j & 7, l = (j >> 3) & 63, kt = (j >> 9) & 7, ig = j >> 12;
                int c = ig * 16 + (l & 15);
                int k = kt * 32 + (l >> 4) * 8 + e;
                W2pA[j] = f2bf(wproj[k * 256 + c]);
            }
        }
        return;
    }
    int h = blockIdx.x;
    int b = blockIdx.y;
    int t = threadIdx.x;
    int p = t >> 7, w = t & 127;
    const float* xb = x + (size_t)b * C_ * HW_ + (size_t)h * W_;
    float s = 0.f, ss = 0.f;
    #pragma unroll 8
    for (int it = 0; it < 128; ++it) {
        int c = it * 2 + p;
        float v = xb[(size_t)c * HW_ + w];
        s += v; ss += v * v;
        sv[c][w] = f2bf(v);
    }
    ps[p][w] = s;
    pss[p][w] = ss;
    __syncthreads();
    if (t < 128) {
        float st = ps[0][t] + ps[1][t];
        float sst = pss[0][t] + pss[1][t];
        float m = st * (1.f / C_);
        float var = sst * (1.f / C_) - m * m;
        mval[t] = m;
        rval[t] = rsqrtf(var + EPS);
    }
    __syncthreads();
    int hp = (h - SHIFT) & 127;
    int wh = hp >> 3, r = hp & 7;
    int i_f = r >> 1;                 // token = r*8+s -> frag i
    int lrb = (r & 1) * 8;            // frag lane-row base
    int c = t;
    float gc = g[c], bc = beta[c];
    int kt = c >> 5, lk2 = (c >> 3) & 3, e = c & 7;
    int winrow = (b * 16 + wh) * 16;
    u16* dst = ywin2 + (size_t)winrow * 16384 + kt * 2048 + i_f * 512 + lk2 * 128 + lrb * 8 + e;
    #pragma unroll 4
    for (int wp = 0; wp < 128; ++wp) {
        int wsrc = (wp + SHIFT) & 127;
        float v = bf2f(sv[c][wsrc]);
        float yv = (v - mval[wsrc]) * rval[wsrc] * gc + bc;
        dst[(size_t)(wp >> 3) * 16384 + (wp & 7) * 8] = f2bf(yv);
    }
}

// ---------------- K2: MEGA: qkv + attention + proj + residual, per-wave head ownership ----------------
// 1 block = 1 window, 512 thr = 8 waves, wave = head. LDS 80 KiB -> 2 blocks/CU.
// Per-wave region 10240 B: Q[64][40] @0 | K[64][40] @2560u16; VT[32][72] overlays Q;
// Phalf[64][40] overlays K. O[64][280] overlays everything after barrier.
__global__ __launch_bounds__(512, 4) void k_fused(const u16* __restrict__ ywin2,
                                                  const u16* __restrict__ W2q,
                                                  const u16* __restrict__ W2pA,
                                                  const float* __restrict__ bqkv,
                                                  const float* __restrict__ bproj,
                                                  const float* __restrict__ x,
                                                  float* __restrict__ out) {
    extern __shared__ __align__(16) char smem[];
    int bid = blockIdx.x;
    int win = (bid & 7) * 256 + (bid >> 3);      // XCD-chunked
    int b = win >> 8, wh = (win >> 4) & 15, ww = win & 15;
    int t = threadIdx.x;
    int wave = t >> 6, lane = t & 63;
    int lr = lane & 15, lk = lane >> 4;
    int hd = wave;

    u16* WR = (u16*)smem + wave * 5120;   // u16 units
    u16* Q  = WR;
    u16* K  = WR + 2560;
    u16* VT = WR;          // overlay Q (Q dead after qf reads)
    u16* Ph = WR + 2560;   // overlay K (K dead after kf reads)
    u16* O  = (u16*)smem;  // [64][280] after barrier

    const u16* afp = ywin2 + (size_t)win * 16384;

    // ---- qk-pass: acc[i][jl], jl: 0,1=q d0/d1; 2,3=k d0/d1 ----
    f32x4 acc[4][4];
    #pragma unroll
    for (int i = 0; i < 4; ++i)
        #pragma unroll
        for (int j = 0; j < 4; ++j) acc[i][j] = (f32x4){0.f,0.f,0.f,0.f};
    #pragma unroll 2
    for (int kt = 0; kt < 8; ++kt) {
        bf16x8 af[4], bq[4];
        #pragma unroll
        for (int i = 0; i < 4; ++i)
            af[i] = __builtin_bit_cast(bf16x8, *(const u16x8*)(afp + kt * 2048 + i * 512 + lane * 8));
        #pragma unroll
        for (int jl = 0; jl < 4; ++jl) {
            int jg = (jl >> 1) * 16 + 2 * hd + (jl & 1);
            bq[jl] = __builtin_bit_cast(bf16x8, *(const u16x8*)(W2q + ((size_t)(jg * 8 + kt)) * 512 + lane * 8));
        }
        #pragma unroll
        for (int i = 0; i < 4; ++i)
            #pragma unroll
            for (int jl = 0; jl < 4; ++jl)
                acc[i][jl] = __builtin_amdgcn_mfma_f32_16x16x32_bf16(af[i], bq[jl], acc[i][jl], 0, 0, 0);
    }
    // stage Q, K (pad-40)
    #pragma unroll
    for (int jl = 0; jl < 4; ++jl) {
        int which = jl >> 1;
        int d = (jl & 1) * 16 + lr;
        float bi = bqkv[which * 256 + hd * 32 + d];
        u16* dst = which ? K : Q;
        #pragma unroll
        for (int i = 0; i < 4; ++i)
            #pragma unroll
            for (int rg = 0; rg < 4; ++rg)
                dst[(i * 16 + lk * 4 + rg) * 40 + d] = f2bf(acc[i][jl][rg] + bi);
    }
    // ---- S = Q K^T ----
    bf16x8 qf[4], kf[4];
    #pragma unroll
    for (int i = 0; i < 4; ++i)
        qf[i] = __builtin_bit_cast(bf16x8, *(const u16x8*)(&Q[(i * 16 + lr) * 40 + lk * 8]));
    #pragma unroll
    for (int j = 0; j < 4; ++j)
        kf[j] = __builtin_bit_cast(bf16x8, *(const u16x8*)(&K[(j * 16 + lr) * 40 + lk * 8]));
    f32x4 s[4][4];
    #pragma unroll
    for (int i = 0; i < 4; ++i)
        #pragma unroll
        for (int j = 0; j < 4; ++j) s[i][j] = (f32x4){0.f,0.f,0.f,0.f};
    #pragma unroll
    for (int i = 0; i < 4; ++i)
        #pragma unroll
        for (int j = 0; j < 4; ++j)
            s[i][j] = __builtin_amdgcn_mfma_f32_16x16x32_bf16(qf[i], kf[j], s[i][j], 0, 0, 0);

    // ---- softmax (max-sub, wave-parallel over 16-lane groups) ----
    const float scale = 0.17677669529663687f;   // 32^-0.5
    #pragma unroll
    for (int i = 0; i < 4; ++i) {
        #pragma unroll
        for (int rg = 0; rg < 4; ++rg) {
            float s0 = s[i][0][rg] * scale, s1 = s[i][1][rg] * scale;
            float s2 = s[i][2][rg] * scale, s3 = s[i][3][rg] * scale;
            float mx = fmaxf(fmaxf(s0, s1), fmaxf(s2, s3));
            mx = fmaxf(mx, __shfl_xor(mx, 1));
            mx = fmaxf(mx, __shfl_xor(mx, 2));
            mx = fmaxf(mx, __shfl_xor(mx, 4));
            mx = fmaxf(mx, __shfl_xor(mx, 8));
            float p0 = __expf(s0 - mx), p1 = __expf(s1 - mx);
            float p2 = __expf(s2 - mx), p3 = __expf(s3 - mx);
            float sm = p0 + p1 + p2 + p3;
            sm += __shfl_xor(sm, 1);
            sm += __shfl_xor(sm, 2);
            sm += __shfl_xor(sm, 4);
            sm += __shfl_xor(sm, 8);
            float rs = 1.f / sm;
            s[i][0][rg] = p0 * rs; s[i][1][rg] = p1 * rs;
            s[i][2][rg] = p2 * rs; s[i][3][rg] = p3 * rs;
        }
    }
    // write P half 0 (k 0..31)
    #pragma unroll
    for (int j2 = 0; j2 < 2; ++j2)
        #pragma unroll
        for (int i = 0; i < 4; ++i)
            #pragma unroll
            for (int rg = 0; rg < 4; ++rg)
                Ph[(i * 16 + lk * 4 + rg) * 40 + j2 * 16 + lr] = f2bf(s[i][j2][rg]);

    // ---- v-pass: av[i][jl] ----
    f32x4 av[4][2];
    #pragma unroll
    for (int i = 0; i < 4; ++i)
        #pragma unroll
        for (int j = 0; j < 2; ++j) av[i][j] = (f32x4){0.f,0.f,0.f,0.f};
    #pragma unroll 2
    for (int kt = 0; kt < 8; ++kt) {
        bf16x8 af[4], bv[2];
        #pragma unroll
        for (int i = 0; i < 4; ++i)
            af[i] = __builtin_bit_cast(bf16x8, *(const u16x8*)(afp + kt * 2048 + i * 512 + lane * 8));
        #pragma unroll
        for (int jl = 0; jl < 2; ++jl) {
            int jg = 32 + 2 * hd + jl;
            bv[jl] = __builtin_bit_cast(bf16x8, *(const u16x8*)(W2q + ((size_t)(jg * 8 + kt)) * 512 + lane * 8));
        }
        #pragma unroll
        for (int i = 0; i < 4; ++i)
            #pragma unroll
            for (int jl = 0; jl < 2; ++jl)
                av[i][jl] = __builtin_amdgcn_mfma_f32_16x16x32_bf16(af[i], bv[jl], av[i][jl], 0, 0, 0);
    }
    // VT[d][tok] pad-72, packed b64 writes (VT overlays Q)
    #pragma unroll
    for (int jl = 0; jl < 2; ++jl) {
        float bi = bqkv[512 + hd * 32 + jl * 16 + lr];
        #pragma unroll
        for (int i = 0; i < 4; ++i) {
            u16x4 pk;
            #pragma unroll
            for (int rg = 0; rg < 4; ++rg) pk[rg] = f2bf(av[i][jl][rg] + bi);
            *(u16x4*)(&VT[(jl * 16 + lr) * 72 + i * 16 + lk * 4]) = pk;
        }
    }
    // ---- PV, half 0 ----
    f32x4 oacc[4][2];
    #pragma unroll
    for (int i = 0; i < 4; ++i)
        #pragma unroll
        for (int j = 0; j < 2; ++j) oacc[i][j] = (f32x4){0.f,0.f,0.f,0.f};
    {
        bf16x8 pf[4], vf[2];
        #pragma unroll
        for (int i = 0; i < 4; ++i)
            pf[i] = __builtin_bit_cast(bf16x8, *(const u16x8*)(&Ph[(i * 16 + lr) * 40 + lk * 8]));
        #pragma unroll
        for (int j = 0; j < 2; ++j)
            vf[j] = __builtin_bit_cast(bf16x8, *(const u16x8*)(&VT[(j * 16 + lr) * 72 + lk * 8]));
        #pragma unroll
        for (int i = 0; i < 4; ++i)
            #pragma unroll
            for (int j = 0; j < 2; ++j)
                oacc[i][j] = __builtin_amdgcn_mfma_f32_16x16x32_bf16(pf[i], vf[j], oacc[i][j], 0, 0, 0);
    }
    // write P half 1 (k 32..63) into same Ph region (same-wave DS ordering)
    #pragma unroll
    for (int j2 = 2; j2 < 4; ++j2)
        #pragma unroll
        for (int i = 0; i < 4; ++i)
            #pragma unroll
            for (int rg = 0; rg < 4; ++rg)
                Ph[(i * 16 + lk * 4 + rg) * 40 + (j2 & 1) * 16 + lr] = f2bf(s[i][j2][rg]);
    // ---- PV, half 1 ----
    {
        bf16x8 pf[4], vf[2];
        #pragma unroll
        for (int i = 0; i < 4; ++i)
            pf[i] = __builtin_bit_cast(bf16x8, *(const u16x8*)(&Ph[(i * 16 + lr) * 40 + lk * 8]));
        #pragma unroll
        for (int j = 0; j < 2; ++j)
            vf[j] = __builtin_bit_cast(bf16x8, *(const u16x8*)(&VT[(j * 16 + lr) * 72 + 32 + lk * 8]));
        #pragma unroll
        for (int i = 0; i < 4; ++i)
            #pragma unroll
            for (int j = 0; j < 2; ++j)
                oacc[i][j] = __builtin_amdgcn_mfma_f32_16x16x32_bf16(pf[i], vf[j], oacc[i][j], 0, 0, 0);
    }

    __syncthreads();   // all waves done with private regions -> O overlay safe
    // O[tok][c] pad-280
    #pragma unroll
    for (int i = 0; i < 4; ++i)
        #pragma unroll
        for (int j = 0; j < 2; ++j)
            #pragma unroll
            for (int rg = 0; rg < 4; ++rg)
                O[(i * 16 + lk * 4 + rg) * 280 + hd * 32 + j * 16 + lr] = f2bf(oacc[i][j][rg]);
    __syncthreads();

    // ---- proj (swapped): D[c][tok], wave covers c = wave*32 .. +31 ----
    f32x4 c2[2][4];
    #pragma unroll
    for (int i = 0; i < 2; ++i)
        #pragma unroll
        for (int j = 0; j < 4; ++j) c2[i][j] = (f32x4){0.f,0.f,0.f,0.f};
    #pragma unroll 2
    for (int kt = 0; kt < 8; ++kt) {
        bf16x8 a2[2], bo[4];
        #pragma unroll
        for (int i2 = 0; i2 < 2; ++i2)
            a2[i2] = __builtin_bit_cast(bf16x8,
                *(const u16x8*)(W2pA + ((size_t)((wave * 2 + i2) * 8 + kt)) * 512 + lane * 8));
        #pragma unroll
        for (int j = 0; j < 4; ++j)
            bo[j] = __builtin_bit_cast(bf16x8, *(const u16x8*)(&O[(j * 16 + lr) * 280 + kt * 32 + lk * 8]));
        #pragma unroll
        for (int i2 = 0; i2 < 2; ++i2)
            #pragma unroll
            for (int j = 0; j < 4; ++j)
                c2[i2][j] = __builtin_amdgcn_mfma_f32_16x16x32_bf16(a2[i2], bo[j], c2[i2][j], 0, 0, 0);
    }

    // ---- epilogue: out[b][c][hs][ws] = 2*(proj + bproj + x) ----
    {
        int hbase = wh * 8 + SHIFT;
        int wbase = ww * 8 + SHIFT;
        #pragma unroll
        for (int i = 0; i < 2; ++i)
            #pragma unroll
            for (int rg = 0; rg < 4; ++rg) {
                int c = wave * 32 + i * 16 + lk * 4 + rg;
                float bi = bproj[c];
                size_t cb = ((size_t)(b * 256 + c)) << 14;
                #pragma unroll
                for (int j = 0; j < 4; ++j) {
                    int token = j * 16 + lr;
                    int r = token >> 3, sgm = token & 7;
                    int hs = (hbase + r) & 127;
                    int wc = (wbase + sgm) & 127;
                    size_t oi = cb + hs * 128 + wc;
                    out[oi] = 2.f * (c2[i][j][rg] + bi + x[oi]);
                }
            }
    }
}

extern "C" void kernel_launch(void* const* d_in, const int* in_sizes, int n_in,
                              void* d_out, int out_size, void* d_ws, size_t ws_size,
                              hipStream_t stream) {
    const float* x     = (const float*)d_in[0];
    const float* g1    = (const float*)d_in[1];
    const float* bb1   = (const float*)d_in[2];
    const float* wqkv  = (const float*)d_in[3];
    const float* bqkv  = (const float*)d_in[4];
    const float* wproj = (const float*)d_in[5];
    const float* bproj = (const float*)d_in[6];
    float* out = (float*)d_out;

    char* ws = (char*)d_ws;
    u16* W2q  = (u16*)ws;                          // 384 KiB
    u16* W2pA = (u16*)(ws + 393216);               // 128 KiB
    u16* ywin2 = (u16*)(ws + (1ull << 20));        // 64 MiB frag-ordered

    static const int LDS_BYTES = 81920;
    hipFuncSetAttribute((const void*)k_fused,
                        hipFuncAttributeMaxDynamicSharedMemorySize, LDS_BYTES);

    k_ln_win<<<dim3(192, 8), 256, 0, stream>>>(x, g1, bb1, ywin2, wqkv, wproj, W2q, W2pA);
    k_fused<<<NWIN, 512, LDS_BYTES, stream>>>(ywin2, W2q, W2pA, bqkv, bproj, x, out);
}